// Round 5
// baseline (407.196 us; speedup 1.0000x reference)
//
#include <hip/hip_runtime.h>

// ---------------------------------------------------------------------------
// Fused MHA block on MI355X (gfx950). fp16 MFMA 16x16x32, fp32 accum.
// Round-12:
//  * QKV GEMM restructured for 2-blocks/CU occupancy: 128x256 tile, BK=32,
//    256 threads (4 waves 1Mx4N, wave tile 128x64), LDS 48 KiB -> 2 blocks
//    co-resident per CU; grid 768 = exactly 3 blocks/CU (no 1.5-round tail,
//    which cost r9-r11 a 0.75x packing factor). Cross-block overlap covers
//    barrier/vmcnt dead time (m97 mechanism) -- r8-r11 all had 1 block/CU
//    (256 unified regs/wave x 8 waves) and pinned at 33-36% MfmaUtil.
//    2 phases/K-tile (16 independent MFMA each), lag-1 fragment reads, ONE
//    counted vmcnt(4) per tile. FIFO ledger (verified): stage B(t+2)@P0,
//    A(t+2)@P1; VMW(4)@P0 end retires [B(t+1),A(t+1)] before their reads at
//    P1(t); af47(t) staged 2 tiles back ✓. Bank swizzle re-derived for 64B
//    row stride: ch = l4 ^ ((l15>>1)&3), matching source pre-swizzle.
//  * wo GEMM (r7-verified 128x128) and flash_attn / cvt_all unchanged.
// ---------------------------------------------------------------------------

typedef _Float16 half8 __attribute__((ext_vector_type(8)));
typedef _Float16 half4 __attribute__((ext_vector_type(4)));
typedef float floatx4 __attribute__((ext_vector_type(4)));

__device__ __forceinline__ void async16(const void* g, void* l) {
  __builtin_amdgcn_global_load_lds((__attribute__((address_space(1))) void*)(g),
                                   (__attribute__((address_space(3))) void*)(l),
                                   16, 0, 0);
}

// ---- fp32 -> fp16 convert: x (2^21 quads) then 4 weights (2^20 each) -------
__global__ void cvt_all(const float* __restrict__ x, const float* __restrict__ w0,
                        const float* __restrict__ w1, const float* __restrict__ w2,
                        const float* __restrict__ w3, _Float16* __restrict__ xh,
                        _Float16* __restrict__ wh, float scale0) {
  int i = blockIdx.x * blockDim.x + threadIdx.x;
  const int XQ = 1 << 21;
  float sc = 1.0f;
  const float* src;
  _Float16* dst;
  int j;
  if (i < XQ) { src = x; dst = xh; j = i; }
  else {
    int t = i - XQ;
    int m = t >> 20;
    src = (m == 0) ? w0 : (m == 1) ? w1 : (m == 2) ? w2 : w3;
    if (m == 0) sc = scale0;
    dst = wh; j = t;
  }
  int js = (i < XQ) ? j : (j & ((1 << 20) - 1));
  float4 v = reinterpret_cast<const float4*>(src)[js];
  union { _Float16 h[4]; short4 s; } u;
  u.h[0] = (_Float16)(v.x * sc); u.h[1] = (_Float16)(v.y * sc);
  u.h[2] = (_Float16)(v.z * sc); u.h[3] = (_Float16)(v.w * sc);
  reinterpret_cast<short4*>(dst)[j] = u.s;
}

// ---- QKV GEMM helpers ------------------------------------------------------
__device__ __forceinline__ void rdA(half8 (&f)[4], const _Float16* base) {
#pragma unroll
  for (int mt = 0; mt < 4; ++mt)
    f[mt] = *reinterpret_cast<const half8*>(base + mt * 512);   // 16 rows * 32
}
__device__ __forceinline__ void rdB(half8 (&f)[4], const _Float16* base) {
#pragma unroll
  for (int nt = 0; nt < 4; ++nt)
    f[nt] = *reinterpret_cast<const half8*>(base + nt * 2048);  // 64 rows * 32
}
template <int MO>
__device__ __forceinline__ void mm16(floatx4 (&acc)[8][4], const half8 (&af)[4],
                                     const half8 (&bf)[4]) {
#pragma unroll
  for (int mt = 0; mt < 4; ++mt)
#pragma unroll
    for (int nt = 0; nt < 4; ++nt)
      acc[MO + mt][nt] = __builtin_amdgcn_mfma_f32_16x16x32_f16(
          af[mt], bf[nt], acc[MO + mt][nt], 0, 0, 0);
}

#define STAGE_B(buf, kk) { async16(bgs + (kk), &Bs[buf][bdst]); \
  async16(bgs + 131072 + (kk), &Bs[buf][bdst + 2048]); \
  async16(bgs + 262144 + (kk), &Bs[buf][bdst + 4096]); \
  async16(bgs + 393216 + (kk), &Bs[buf][bdst + 6144]); }
#define STAGE_A(buf, kk) { async16(ags + (kk), &As[buf][adst]); \
  async16(ags + 131072 + (kk), &As[buf][adst + 2048]); }
#define VMW(n) asm volatile("s_waitcnt vmcnt(" #n ")" ::: "memory")
#define SBAR() __builtin_amdgcn_s_barrier()
#define SCHED() __builtin_amdgcn_sched_barrier(0)
#define PRIO1() __builtin_amdgcn_s_setprio(1)
#define PRIO0() __builtin_amdgcn_s_setprio(0)

// ---- QKV NT GEMM (16x16x32): C[m][n] = sum_k A[m][k]*Bw[n][k] --------------
// 128x256 tile, BK=32, 256 threads, 4 waves 1Mx4N, wave tile 128x64.
// LDS 48 KiB -> 2 blocks/CU; grid 768 = 3 blocks/CU exact.
__global__ __launch_bounds__(256, 2)
void gemm_nt(const _Float16* __restrict__ A, const _Float16* __restrict__ Bw,
             void* __restrict__ Cv, void* __restrict__ Cv2) {
  __shared__ _Float16 As[2][128 * 32];   // 8 KiB each
  __shared__ _Float16 Bs[2][256 * 32];   // 16 KiB each
  const int tid = threadIdx.x;
  const int wn = tid >> 6, lane = tid & 63;   // 4 waves across N
  const int l15 = lane & 15, l4 = lane >> 4;

  // XCD swizzle, bn-fastest chunks: each XCD = 4 bm-rows x 24 bn.
  const int swz = (blockIdx.x & 7) * 96 + (blockIdx.x >> 3);
  const int bn = swz % 24, bm = swz / 24;

  // Staging: xor-swizzled global source, linear LDS dest.
  const int srow = tid >> 2;                  // 0..63 (per 64-row group)
  const int sg = (tid & 3) ^ ((srow >> 1) & 3);
  const _Float16* ags = A + (size_t)(bm * 128 + srow) * 2048 + sg * 8;
  const _Float16* bgs = Bw + (size_t)(bn * 256 + srow) * 2048 + sg * 8;
  const int adst = tid * 8, bdst = tid * 8;

  // Fragment read coords (row stride 32 halves = 64 B; 2-way bank = free).
  const int rch = (l4 ^ ((l15 >> 1) & 3)) * 8;
  const int abase = l15 * 32 + rch;                 // + mt*512 (+2048 for m4-7)
  const int bbase = (wn * 16 + l15) * 32 + rch;     // + nt*2048

  // Prologue: stage tiles 0,1; retire tile 0; pre-read t0 operands.
  STAGE_B(0, 0); STAGE_A(0, 0);
  STAGE_B(1, 32); STAGE_A(1, 32);
  VMW(6); SBAR();

  floatx4 acc[8][4] = {};
  half8 afL[4], afH[4], bf[4];
  rdA(afL, &As[0][abase]);
  rdB(bf, &Bs[0][bbase]);

#pragma unroll 2
  for (int t = 0; t < 62; ++t) {
    const int c = t & 1, nx = c ^ 1;
    const int kn = t * 32 + 64;               // global k of tile t+2

    // P0: MFMA rows 0-63; read af rows 64-127(t); stage B(t+2)->buf[c]
    PRIO1(); mm16<0>(acc, afL, bf); PRIO0();
    rdA(afH, &As[c][abase + 2048]);
    STAGE_B(c, kn);
    SCHED(); VMW(4); SBAR();                  // retires B(t+1),A(t+1)

    // P1: MFMA rows 64-127; read afL/bf(t+1); stage A(t+2)->buf[c]
    PRIO1(); mm16<4>(acc, afH, bf); PRIO0();
    rdA(afL, &As[nx][abase]);
    rdB(bf, &Bs[nx][bbase]);
    STAGE_A(c, kn);
    SCHED(); SBAR();
  }
  // ---- peeled t=62 (c=0): no staging; drain for t=63 reads ----
  PRIO1(); mm16<0>(acc, afL, bf); PRIO0();
  rdA(afH, &As[0][abase + 2048]);
  SCHED(); VMW(0); SBAR();                    // retires B(63),A(63)
  PRIO1(); mm16<4>(acc, afH, bf); PRIO0();
  rdA(afL, &As[1][abase]);
  rdB(bf, &Bs[1][bbase]);
  SBAR();
  // ---- peeled t=63 (c=1) ----
  mm16<0>(acc, afL, bf);
  rdA(afH, &As[1][abase + 2048]);
  mm16<4>(acc, afH, bf);

  // ---- fused QKV epilogue (row = bm*128 + mt*16 + l4*4 + r,
  //                          col = bn*256 + nt*64 + wn*16 + l15) ----
  const int cb0 = bn * 256;
  if (cb0 < 4096) {             // Q or K: row-major fp16, ld 2048
    _Float16* C = (_Float16*)Cv + (size_t)(cb0 >> 11) * (4096ull * 2048);
#pragma unroll
    for (int mt = 0; mt < 8; ++mt)
#pragma unroll
      for (int nt = 0; nt < 4; ++nt) {
        int r0 = bm * 128 + mt * 16 + l4 * 4;
        int cg = (cb0 + nt * 64 + wn * 16 + l15) & 2047;
#pragma unroll
        for (int r = 0; r < 4; ++r)
          C[(size_t)(r0 + r) * 2048 + cg] = (_Float16)acc[mt][nt][r];
      }
  } else {                      // V: per-batch transposed [b][d][s]
    _Float16* C = (_Float16*)Cv2;
#pragma unroll
    for (int mt = 0; mt < 8; ++mt)
#pragma unroll
      for (int nt = 0; nt < 4; ++nt) {
        int m0 = bm * 128 + mt * 16 + l4 * 4;
        int d = cb0 + nt * 64 + wn * 16 + l15 - 4096;
        size_t base = (size_t)(m0 >> 11) * (2048ull * 2048) + (size_t)d * 2048 + (m0 & 2047);
        union { _Float16 h[4]; short4 s; } u;
#pragma unroll
        for (int r = 0; r < 4; ++r) u.h[r] = (_Float16)acc[mt][nt][r];
        *reinterpret_cast<short4*>(C + base) = u.s;
      }
  }
}

// ---- wo GEMM: r7-verified 128x128 2-phase NT GEMM, fp32 out ----------------
__global__ __launch_bounds__(256)
void gemm_wo(const _Float16* __restrict__ A, const _Float16* __restrict__ Bw,
             float* __restrict__ C) {
  __shared__ _Float16 As[128 * 64];
  __shared__ _Float16 Bs[128 * 64];
  const int tid = threadIdx.x;
  const int wave = tid >> 6, lane = tid & 63;
  const int wm = wave >> 1, wn = wave & 1;
  const int l15 = lane & 15, l4 = lane >> 4;
  const int bm = blockIdx.y, bn = blockIdx.x;

  floatx4 acc[4][4] = {};

  for (int k0 = 0; k0 < 2048; k0 += 64) {
    __syncthreads();
#pragma unroll
    for (int i = 0; i < 4; ++i) {
      int c = i * 256 + tid;
      int row = c >> 3, cc = c & 7;
      int gg = cc ^ (row & 7);
      async16(A + (size_t)(bm * 128 + row) * 2048 + k0 + gg * 8, &As[c * 8]);
      async16(Bw + (size_t)(bn * 128 + row) * 2048 + k0 + gg * 8, &Bs[c * 8]);
    }
    __syncthreads();
#pragma unroll
    for (int ks = 0; ks < 2; ++ks) {
      half8 af[4], bf[4];
      int ch = (ks * 4 + l4) ^ (l15 & 7);
#pragma unroll
      for (int t = 0; t < 4; ++t) {
        af[t] = *reinterpret_cast<const half8*>(&As[(wm * 64 + t * 16 + l15) * 64 + ch * 8]);
        bf[t] = *reinterpret_cast<const half8*>(&Bs[(wn * 64 + t * 16 + l15) * 64 + ch * 8]);
      }
#pragma unroll
      for (int mt = 0; mt < 4; ++mt)
#pragma unroll
        for (int nt = 0; nt < 4; ++nt)
          acc[mt][nt] = __builtin_amdgcn_mfma_f32_16x16x32_f16(af[mt], bf[nt], acc[mt][nt], 0, 0, 0);
    }
  }

  const int rbase = bm * 128 + wm * 64;
  const int cbase = bn * 128 + wn * 64;
#pragma unroll
  for (int mt = 0; mt < 4; ++mt)
#pragma unroll
    for (int nt = 0; nt < 4; ++nt) {
      int r0 = rbase + mt * 16 + l4 * 4;
      int cg = cbase + nt * 16 + l15;
#pragma unroll
      for (int r = 0; r < 4; ++r)
        C[(size_t)(r0 + r) * 2048 + cg] = acc[mt][nt][r];
    }
}

// ---- Flash attention (unchanged, round-7 verified) --------------------------
// grid = (16 q-tiles of 128, 32 b*h); block = 256 (4 waves x 32 q rows).
__global__ __launch_bounds__(256, 2)
void flash_attn(const _Float16* __restrict__ Q, const _Float16* __restrict__ Kg,
                const _Float16* __restrict__ Vt, _Float16* __restrict__ O) {
  __shared__ _Float16 Ks[64 * 128];   // [key][hd], 16-chunk xor swizzle
  __shared__ _Float16 Vs[128 * 64];   // [d][s],    8-chunk xor swizzle
  __shared__ _Float16 Ps[128 * 64];   // [q][key],  8-chunk xor swizzle
  const int tid = threadIdx.x, wave = tid >> 6, lane = tid & 63;
  const int l15 = lane & 15, l4 = lane >> 4;
  const int bh = blockIdx.y, b = bh >> 4, h = bh & 15;
  const int q0 = blockIdx.x * 128;

  const _Float16* Qp = Q + ((size_t)(b * 2048 + q0 + wave * 32)) * 2048 + h * 128;
  const _Float16* Kp = Kg + (size_t)b * 2048 * 2048 + h * 128;
  const _Float16* Vp = Vt + (size_t)b * 2048 * 2048 + (size_t)(h * 128) * 2048;

  half8 qf[2][4];
#pragma unroll
  for (int qt = 0; qt < 2; ++qt)
#pragma unroll
    for (int ks = 0; ks < 4; ++ks)
      qf[qt][ks] = *reinterpret_cast<const half8*>(
          Qp + (size_t)(qt * 16 + l15) * 2048 + ks * 32 + l4 * 8);

  floatx4 oacc[2][8] = {};
  float lsumq[2] = {0.f, 0.f};        // per-lane: sum over its s for q = lane&15

  for (int k0 = 0; k0 < 2048; k0 += 64) {
    __syncthreads();
#pragma unroll
    for (int i = 0; i < 4; ++i) {                 // K: 64 rows x 16 chunks
      int c = i * 256 + tid;
      int row = c >> 4, cc = c & 15;
      int g = cc ^ (row & 15);
      async16(Kp + (size_t)(k0 + row) * 2048 + g * 8, &Ks[c * 8]);
    }
#pragma unroll
    for (int i = 0; i < 4; ++i) {                 // V: 128 rows x 8 chunks
      int c = i * 256 + tid;
      int row = c >> 3, cc = c & 7;
      int g = cc ^ (row & 7);
      async16(Vp + (size_t)row * 2048 + k0 + g * 8, &Vs[c * 8]);
    }
    __syncthreads();

    // ---- S^T = K Q^T : sacc[st][qt], col=q, row=s ----
    floatx4 sacc[4][2] = {};
#pragma unroll
    for (int ks = 0; ks < 4; ++ks) {
      half8 kf[4];
#pragma unroll
      for (int st = 0; st < 4; ++st) {
        int row = st * 16 + l15;
        int ch = (ks * 4 + l4) ^ l15;             // row & 15 == l15
        kf[st] = *reinterpret_cast<const half8*>(&Ks[row * 128 + ch * 8]);
      }
#pragma unroll
      for (int st = 0; st < 4; ++st)
#pragma unroll
        for (int qt = 0; qt < 2; ++qt)
          sacc[st][qt] = __builtin_amdgcn_mfma_f32_16x16x32_f16(kf[st], qf[qt][ks], sacc[st][qt], 0, 0, 0);
    }

    // ---- p = 2^s; packed b64 Ps write (4 consecutive s per lane) ----
#pragma unroll
    for (int qt = 0; qt < 2; ++qt)
#pragma unroll
      for (int st = 0; st < 4; ++st) {
        float p0 = exp2f(sacc[st][qt][0]);
        float p1 = exp2f(sacc[st][qt][1]);
        float p2 = exp2f(sacc[st][qt][2]);
        float p3 = exp2f(sacc[st][qt][3]);
        lsumq[qt] += (p0 + p1) + (p2 + p3);
        half4 pv;
        pv[0] = (_Float16)p0; pv[1] = (_Float16)p1;
        pv[2] = (_Float16)p2; pv[3] = (_Float16)p3;
        int ch = (st * 2 + (l4 >> 1)) ^ (l15 & 7);
        *reinterpret_cast<half4*>(
            &Ps[(wave * 32 + qt * 16 + l15) * 64 + ch * 8 + (l4 & 1) * 4]) = pv;
      }

    __builtin_amdgcn_s_waitcnt(0xC07F);  // lgkmcnt(0): own-wave ds_write->ds_read

    // ---- O += P V  (V stored (d,s): NT GEMM) ----
#pragma unroll
    for (int ks2 = 0; ks2 < 2; ++ks2) {
      half8 pf[2];
#pragma unroll
      for (int mt = 0; mt < 2; ++mt)
        pf[mt] = *reinterpret_cast<const half8*>(
            &Ps[(wave * 32 + mt * 16 + l15) * 64 + (((ks2 * 4 + l4) ^ (l15 & 7)) * 8)]);
#pragma unroll
      for (int nt2 = 0; nt2 < 8; ++nt2) {
        int row = nt2 * 16 + l15;
        int ch = (ks2 * 4 + l4) ^ (row & 7);
        half8 vf = *reinterpret_cast<const half8*>(&Vs[row * 64 + ch * 8]);
#pragma unroll
        for (int mt = 0; mt < 2; ++mt)
          oacc[mt][nt2] = __builtin_amdgcn_mfma_f32_16x16x32_f16(pf[mt], vf, oacc[mt][nt2], 0, 0, 0);
      }
    }
  }

#pragma unroll
  for (int qt = 0; qt < 2; ++qt) {
    lsumq[qt] += __shfl_xor(lsumq[qt], 16);
    lsumq[qt] += __shfl_xor(lsumq[qt], 32);
  }

  _Float16* Op = O + ((size_t)(b * 2048 + q0 + wave * 32)) * 2048 + h * 128;
#pragma unroll
  for (int mt = 0; mt < 2; ++mt)
#pragma unroll
    for (int r = 0; r < 4; ++r) {
      float inv = 1.0f / __shfl(lsumq[mt], l4 * 4 + r);
#pragma unroll
      for (int nt2 = 0; nt2 < 8; ++nt2) {
        int row = mt * 16 + l4 * 4 + r;
        int col = nt2 * 16 + l15;
        Op[(size_t)row * 2048 + col] = (_Float16)(oacc[mt][nt2][r] * inv);
      }
    }
}

// ---------------------------------------------------------------------------
extern "C" void kernel_launch(void* const* d_in, const int* in_sizes, int n_in,
                              void* d_out, int out_size, void* d_ws, size_t ws_size,
                              hipStream_t stream) {
  const float* x = (const float*)d_in[0];
  const float* wq = (const float*)d_in[1];
  const float* wk = (const float*)d_in[2];
  const float* wv = (const float*)d_in[3];
  const float* wo = (const float*)d_in[4];
  float* out = (float*)d_out;

  const size_t XN = (size_t)4096 * 2048;
  const size_t WN = (size_t)2048 * 2048;
  _Float16* xh = (_Float16*)d_ws;
  _Float16* qh = xh + XN;          // Q then K contiguous (row-major, ld 2048)
  _Float16* vth = xh + 3 * XN;     // per-batch transposed V
  _Float16* oh = xh + 4 * XN;
  _Float16* wqh = xh + 5 * XN;     // wq,wk,wv,wo contiguous

  const float SM_SCALE = 0.08838834764831845f * 1.4426950408889634f;

  cvt_all<<<dim3(24576), 256, 0, stream>>>(x, wq, wk, wv, wo, xh, wqh, SM_SCALE);
  gemm_nt<<<dim3(768), 256, 0, stream>>>(xh, wqh, qh, vth);
  flash_attn<<<dim3(16, 32), 256, 0, stream>>>(qh, qh + XN, vth, oh);
  gemm_wo<<<dim3(16, 32), 256, 0, stream>>>(oh, wqh + 3 * WN, out);
}